// Round 20
// baseline (235.008 us; speedup 1.0000x reference)
//
#include <hip/hip_runtime.h>
#include <hip/hip_bf16.h>

// Problem constants
#define BB 8
#define NN_ 1024
#define DD 1024
#define HH 16
#define TT_ 64
#define MM (BB * NN_)   // 8192

typedef __attribute__((ext_vector_type(8))) short short8;
typedef __attribute__((ext_vector_type(4))) float f32x4;
typedef __attribute__((ext_vector_type(4))) unsigned int u32x4;

__device__ __forceinline__ void g2lds16(const void* g, void* l) {
    __builtin_amdgcn_global_load_lds(
        (const __attribute__((address_space(1))) void*)g,
        (__attribute__((address_space(3))) void*)l, 16, 0, 0);
}

__device__ __forceinline__ __hip_bfloat16 f2b(float x) { return __float2bfloat16(x); }
__device__ __forceinline__ float b2f(unsigned short u) {
    unsigned v = (unsigned)u << 16;
    return __builtin_bit_cast(float, v);
}

// pack two f32 -> two bf16 in one u32 (lo = a, hi = b)
__device__ __forceinline__ unsigned cvtpk(float a, float b) {
    unsigned r;
    asm("v_cvt_pk_bf16_f32 %0, %1, %2" : "=v"(r) : "v"(a), "v"(b));
    return r;
}

// bijective XCD swizzle (nwg must be divisible by 8): blocks with the same
// (orig % 8) land on one XCD and get a CONTIGUOUS logical range -> L2 reuse.
__device__ __forceinline__ int xcd_swz(int bid, int nwg) {
    return (bid & 7) * (nwg >> 3) + (bid >> 3);
}

// ---------- merged prep kernel ----------
// blocks [0,8192): tokens f32->bf16 ; [8192,8960): Wqkv transpose ;
// [8960,9472): W1/W2 transpose.
__global__ __launch_bounds__(256) void k_prep(const float* __restrict__ tokens,
                                              const float* __restrict__ Wq,
                                              const float* __restrict__ Wk,
                                              const float* __restrict__ Wv,
                                              const float* __restrict__ W1,
                                              const float* __restrict__ W2,
                                              __hip_bfloat16* __restrict__ tok_b,
                                              __hip_bfloat16* __restrict__ Wqkv_t,
                                              __hip_bfloat16* __restrict__ W1t,
                                              __hip_bfloat16* __restrict__ W2t) {
    __shared__ float tile[64][65];
    const int bid = blockIdx.x;
    if (bid < 8192) {
        int i = (bid * 256 + threadIdx.x) * 4;
        float4 v = *(const float4*)&tokens[i];
        tok_b[i + 0] = f2b(v.x); tok_b[i + 1] = f2b(v.y);
        tok_b[i + 2] = f2b(v.z); tok_b[i + 3] = f2b(v.w);
        return;
    }
    const int c = threadIdx.x & 63, r0 = threadIdx.x >> 6;
    if (bid < 8960) {
        const int q = bid - 8192;                 // 0..767
        const int proj = q >> 8, h = (q >> 4) & 15, dt = q & 15;
        const float* W = proj == 0 ? Wq : (proj == 1 ? Wk : Wv);
        const float* src = W + ((size_t)h * 1024 + dt * 64) * 64;   // [64 d][64 t]
#pragma unroll
        for (int p = 0; p < 16; p++) {
            const int r = p * 4 + r0;
            tile[r][c] = src[(size_t)r * 64 + c];
        }
        __syncthreads();
        __hip_bfloat16* dst = Wqkv_t + (size_t)(proj * 1024 + h * 64) * 1024 + dt * 64;
#pragma unroll
        for (int p = 0; p < 16; p++) {
            const int r = p * 4 + r0;   // t index
            dst[(size_t)r * 1024 + c] = f2b(tile[c][r]);
        }
        return;
    }
    const int q = bid - 8960;                     // 0..511
    const int which = q >> 8, b = q & 255;
    const float* W = which ? W2 : W1;
    __hip_bfloat16* out = which ? W2t : W1t;
    const int ct = b & 15, dt = b >> 4;
    const float* src = W + (size_t)(dt * 64) * 1024 + ct * 64;
#pragma unroll
    for (int p = 0; p < 16; p++) {
        const int r = p * 4 + r0;
        tile[r][c] = src[(size_t)r * 1024 + c];
    }
    __syncthreads();
    __hip_bfloat16* dst = out + (size_t)(ct * 64) * 1024 + dt * 64;
#pragma unroll
    for (int p = 0; p < 16; p++) {
        const int r = p * 4 + r0;
        dst[(size_t)r * 1024 + c] = f2b(tile[c][r]);
    }
}

// ---------- GEMM: A[M][1024] bf16  x  Bt[Ncols][1024] bf16 ----------
// Round-13 proven structure: 8 waves / 512 threads, 128x128 tile, BK=64,
// double-buffered LDS, stage -> vmcnt(4) -> barrier -> compute -> barrier.
// T2 XOR-swizzle, setprio, XCD block swizzle.
// MODE 0: proj -> Q (scaled log2e/32), K, Vt (transposed)
// MODE 1: relu(x@W1+b1) -> bf16
// MODE 2: x@W2 + b2 + res(bf16) -> bf16
template <int MODE>
__global__ __launch_bounds__(512) void k_gemm(
    const __hip_bfloat16* __restrict__ A, const __hip_bfloat16* __restrict__ Bt,
    const float* __restrict__ bias0, const float* __restrict__ bias1,
    const float* __restrict__ bias2,
    __hip_bfloat16* __restrict__ ob0, __hip_bfloat16* __restrict__ ob1,
    __hip_bfloat16* __restrict__ ob2,
    const __hip_bfloat16* __restrict__ res) {
    __shared__ __align__(16) __hip_bfloat16 As[2][128 * 64];
    __shared__ __align__(16) __hip_bfloat16 Bs[2][128 * 64];

    const int tid = threadIdx.x;
    const int wid = tid >> 6, lane = tid & 63;
    const int l15 = lane & 15, lhi = lane >> 4;
    const int wm = wid >> 1, wn = wid & 1;   // 4x2 wave grid: 32-row x 64-col sub-tiles

    const int nbx = gridDim.x;
    int bid = xcd_swz(blockIdx.y * nbx + blockIdx.x, nbx * gridDim.y);
    const int n0 = (bid % nbx) * 128, m0 = (bid / nbx) * 128;

    const int srow = lane >> 3;
    const int scol = ((lane & 7) ^ srow) * 8;   // pre-swizzled global source chunk

    const __hip_bfloat16* gsrc;
    if (wid < 4)
        gsrc = A + (size_t)(m0 + wid * 32 + srow) * 1024 + scol;
    else
        gsrc = Bt + (size_t)(n0 + (wid - 4) * 32 + srow) * 1024 + scol;
    const int lofs = (wid & 3) * 2048;   // 32-row chunk within the tile

    // stage K-tile kt into buffer bufi (4 loads/thread; 8 rows per load)
    auto stage = [&](int kt, int bufi) {
        __hip_bfloat16* lb = (wid < 4) ? &As[bufi][lofs] : &Bs[bufi][lofs];
#pragma unroll
        for (int i = 0; i < 4; ++i)
            g2lds16(gsrc + kt * 64 + (size_t)i * 8 * 1024, lb + i * 512);
    };

    f32x4 acc[2][4];
#pragma unroll
    for (int i = 0; i < 2; i++)
#pragma unroll
        for (int j = 0; j < 4; j++) acc[i][j] = (f32x4){0.f, 0.f, 0.f, 0.f};

    stage(0, 0);
    const int swz = l15 & 7;

    for (int kt = 0; kt < 16; ++kt) {
        const int cur = kt & 1;
        if (kt < 15) {
            stage(kt + 1, cur ^ 1);
            asm volatile("s_waitcnt vmcnt(4)" ::: "memory");  // tile kt resident; kt+1 in flight
        } else {
            asm volatile("s_waitcnt vmcnt(0)" ::: "memory");
        }
        __builtin_amdgcn_s_barrier();
        asm volatile("" ::: "memory");
        __builtin_amdgcn_s_setprio(1);
#pragma unroll
        for (int kk = 0; kk < 2; ++kk) {
            const int ch = ((kk * 4 + lhi) ^ swz) * 8;   // swizzled 16B chunk
            short8 af[2], bfr[4];
#pragma unroll
            for (int mi = 0; mi < 2; mi++)
                af[mi] = *(const short8*)&As[cur][(wm * 32 + mi * 16 + l15) * 64 + ch];
#pragma unroll
            for (int ni = 0; ni < 4; ni++)
                bfr[ni] = *(const short8*)&Bs[cur][(wn * 64 + ni * 16 + l15) * 64 + ch];
#pragma unroll
            for (int mi = 0; mi < 2; mi++)
#pragma unroll
                for (int ni = 0; ni < 4; ni++)
                    acc[mi][ni] = __builtin_amdgcn_mfma_f32_16x16x32_bf16(
                        af[mi], bfr[ni], acc[mi][ni], 0, 0, 0);
        }
        __builtin_amdgcn_s_setprio(0);
        asm volatile("" ::: "memory");
        __builtin_amdgcn_s_barrier();   // all waves done reading buf[cur]
    }

#pragma unroll
    for (int mi = 0; mi < 2; mi++) {
#pragma unroll
        for (int ni = 0; ni < 4; ni++) {
            const int col = n0 + wn * 64 + ni * 16 + l15;
#pragma unroll
            for (int r = 0; r < 4; r++) {
                const int m = m0 + wm * 32 + mi * 16 + lhi * 4 + r;
                float v = acc[mi][ni][r];
                if (MODE == 0) {
                    const int proj = col >> 10, hh = (col >> 6) & 15, t = col & 63;
                    const float* bp = proj == 0 ? bias0 : (proj == 1 ? bias1 : bias2);
                    v += bp[hh * 64 + t];
                    const int b = m >> 10, n = m & 1023;
                    if (proj == 0)   // Q pre-scaled by log2(e)/32 (exp2-base softmax)
                        ob0[((size_t)(b * 16 + hh) * 1024 + n) * 64 + t] = f2b(v * 0.04508422f);
                    else if (proj == 1)
                        ob1[((size_t)(b * 16 + hh) * 1024 + n) * 64 + t] = f2b(v);
                    else
                        ob2[((size_t)(b * 16 + hh) * 64 + t) * 1024 + n] = f2b(v);
                } else if (MODE == 1) {
                    v += bias0[col];
                    ob0[(size_t)m * 1024 + col] = f2b(fmaxf(v, 0.f));
                } else {
                    v += bias0[col] + b2f(*(const unsigned short*)&res[(size_t)m * 1024 + col]);
                    ob0[(size_t)m * 1024 + col] = f2b(v);
                }
            }
        }
    }
}

// ---------- flash attention (swapped-QK, in-register P, no-max softmax) ----------
// 8 waves / 512 threads, QBLK=256; KVBLK=128 as two 64-key halves per
// barrier-pair. h-PIPELINED: QK MFMAs for BOTH halves issue first, then
// softmax(h0) VALU overlaps h1's in-flight MFMAs, PV(h0) overlaps
// softmax(h1), etc. (T15 mechanism: MFMA and VALU are separate pipes.)
// Proven protocol: stage(t+1) -> vmcnt(4) -> barrier -> compute -> barrier.
// Q,K: [B,H,N,64] bf16 (Q pre-scaled by log2e/32); Vt: [B,H,64,N] bf16
// out: attn [B,N,1024] bf16, channel = t*16 + head
__global__ __launch_bounds__(512, 4) void k_attn(const __hip_bfloat16* __restrict__ Q,
                                                 const __hip_bfloat16* __restrict__ Kg,
                                                 const __hip_bfloat16* __restrict__ Vt,
                                                 __hip_bfloat16* __restrict__ attn_out) {
    __shared__ __align__(16) __hip_bfloat16 Ks[2][2][64 * 64];
    __shared__ __align__(16) __hip_bfloat16 Vs[2][2][64 * 64];

    const int tid = threadIdx.x, wid = tid >> 6, lane = tid & 63;
    const int l15 = lane & 15, lhi = lane >> 4;
    const int bid = xcd_swz(blockIdx.x, gridDim.x);   // XCD x gets one full batch
    const int qb = bid & 3, head = (bid >> 2) & 15, b = bid >> 6;
    const int bh = b * 16 + head;
    const __hip_bfloat16* Qg = Q + ((size_t)bh * 1024 + qb * 256) * 64;
    const __hip_bfloat16* Kp = Kg + (size_t)bh * 1024 * 64;
    const __hip_bfloat16* Vp = Vt + (size_t)bh * 64 * 1024;
    const int srow = lane >> 3;
    const int scol = ((lane & 7) ^ srow) * 8;   // pre-swizzled global source chunk

    // stage 128-key K/V tile t into buffer bufi (4 loads/thread);
    // K rows permuted by pi within each 64-key half.
    auto stageKV = [&](int t, int bufi) {
        const int krow = wid * 8 + srow;                           // row in half, 0..63
        const int kperm = (krow & 0x23) | ((krow & 0x0C) << 1) | ((krow & 0x10) >> 2);
#pragma unroll
        for (int h = 0; h < 2; h++) {
            g2lds16(Kp + (size_t)(t * 128 + h * 64 + kperm) * 64 + scol, &Ks[bufi][h][wid * 512]);
            g2lds16(Vp + (size_t)krow * 1024 + t * 128 + h * 64 + scol, &Vs[bufi][h][wid * 512]);
        }
    };

    // Q fragments straight from global (B-operand: lane l15 = q-row within group)
    short8 qf[2][2];
#pragma unroll
    for (int g = 0; g < 2; g++)
#pragma unroll
        for (int c = 0; c < 2; c++)
            qf[g][c] = *(const short8*)&Qg[(size_t)(wid * 32 + g * 16 + l15) * 64 + c * 32 + lhi * 8];

    stageKV(0, 0);

    f32x4 o[2][4];
#pragma unroll
    for (int g = 0; g < 2; g++)
#pragma unroll
        for (int i = 0; i < 4; i++) o[g][i] = (f32x4){0.f, 0.f, 0.f, 0.f};
    f32x4 lacc[2] = {(f32x4){0.f, 0.f, 0.f, 0.f}, (f32x4){0.f, 0.f, 0.f, 0.f}};
    const short bf16_one = (short)0x3F80;
    const short8 ones = (short8){bf16_one, bf16_one, bf16_one, bf16_one,
                                 bf16_one, bf16_one, bf16_one, bf16_one};

    const int sw = l15 & 7;
    const int c0 = (lhi ^ sw) * 8;   // swizzled chunk for LDS rows with row&7 == l15&7

    for (int t = 0; t < 8; ++t) {
        const int cur = t & 1;
        if (t < 7) {
            stageKV(t + 1, cur ^ 1);
            asm volatile("s_waitcnt vmcnt(4)" ::: "memory");  // tile t resident; t+1 in flight
        } else {
            asm volatile("s_waitcnt vmcnt(0)" ::: "memory");
        }
        __builtin_amdgcn_s_barrier();
        asm volatile("" ::: "memory");

        // ---- QK^T for BOTH halves (fills matrix pipe) ----
        f32x4 s[2][2][4];   // [half][g][nt]
        __builtin_amdgcn_s_setprio(1);
#pragma unroll
        for (int h = 0; h < 2; h++) {
            const __hip_bfloat16* Kc = &Ks[cur][h][0];
#pragma unroll
            for (int nt = 0; nt < 4; ++nt) {
                const int kr = (nt * 16 + l15) * 64;   // row&7 == sw
                short8 k0 = *(const short8*)&Kc[kr + c0];
                short8 k1 = *(const short8*)&Kc[kr + (c0 ^ 32)];
#pragma unroll
                for (int g = 0; g < 2; g++) {
                    f32x4 z = (f32x4){0.f, 0.f, 0.f, 0.f};
                    z = __builtin_amdgcn_mfma_f32_16x16x32_bf16(k0, qf[g][0], z, 0, 0, 0);
                    s[h][g][nt] = __builtin_amdgcn_mfma_f32_16x16x32_bf16(k1, qf[g][1], z, 0, 0, 0);
                }
            }
        }
        __builtin_amdgcn_s_setprio(0);

        // ---- softmax(h) on VALU overlaps other half's MFMAs; PV per half ----
        short8 pf[2][2][2];   // [half][g][chunk]
#pragma unroll
        for (int h = 0; h < 2; h++) {
            // p = 2^s (no max subtraction; scores bounded)
#pragma unroll
            for (int g = 0; g < 2; g++)
#pragma unroll
                for (int nt = 0; nt < 4; nt++)
#pragma unroll
                    for (int r = 0; r < 4; r++) s[h][g][nt][r] = __builtin_exp2f(s[h][g][nt][r]);
#pragma unroll
            for (int g = 0; g < 2; g++) {
                u32x4 w0 = (u32x4){cvtpk(s[h][g][0][0], s[h][g][0][1]), cvtpk(s[h][g][0][2], s[h][g][0][3]),
                                   cvtpk(s[h][g][1][0], s[h][g][1][1]), cvtpk(s[h][g][1][2], s[h][g][1][3])};
                u32x4 w1 = (u32x4){cvtpk(s[h][g][2][0], s[h][g][2][1]), cvtpk(s[h][g][2][2], s[h][g][2][3]),
                                   cvtpk(s[h][g][3][0], s[h][g][3][1]), cvtpk(s[h][g][3][2], s[h][g][3][3])};
                pf[h][g][0] = __builtin_bit_cast(short8, w0);
                pf[h][g][1] = __builtin_bit_cast(short8, w1);
            }

            // l += P.1 ; O += P V   (issues while the NEXT half's softmax runs on VALU)
            const __hip_bfloat16* Vc = &Vs[cur][h][0];
            __builtin_amdgcn_s_setprio(1);
#pragma unroll
            for (int g = 0; g < 2; g++) {
                lacc[g] = __builtin_amdgcn_mfma_f32_16x16x32_bf16(pf[h][g][0], ones, lacc[g], 0, 0, 0);
                lacc[g] = __builtin_amdgcn_mfma_f32_16x16x32_bf16(pf[h][g][1], ones, lacc[g], 0, 0, 0);
            }
#pragma unroll
            for (int tt = 0; tt < 4; tt++) {
                const int vr = (tt * 16 + l15) * 64;   // row&7 == sw
                short8 v0 = *(const short8*)&Vc[vr + c0];
                short8 v1 = *(const short8*)&Vc[vr + (c0 ^ 32)];
#pragma unroll
                for (int g = 0; g < 2; g++) {
                    o[g][tt] = __builtin_amdgcn_mfma_f32_16x16x32_bf16(pf[h][g][0], v0, o[g][tt], 0, 0, 0);
                    o[g][tt] = __builtin_amdgcn_mfma_f32_16x16x32_bf16(pf[h][g][1], v1, o[g][tt], 0, 0, 0);
                }
            }
            __builtin_amdgcn_s_setprio(0);
        }
        asm volatile("" ::: "memory");
        __builtin_amdgcn_s_barrier();   // all waves done reading buf[cur]
    }

#pragma unroll
    for (int g = 0; g < 2; g++)
#pragma unroll
        for (int r = 0; r < 4; r++) {
            const float inv_r = 1.f / lacc[g][r];
            const int row = qb * 256 + wid * 32 + g * 16 + lhi * 4 + r;
#pragma unroll
            for (int tt = 0; tt < 4; tt++) {
                const int ch = (tt * 16 + l15) * 16 + head;
                attn_out[((size_t)(b * 1024 + row)) * 1024 + ch] = f2b(o[g][tt][r] * inv_r);
            }
        }
}

// ---------- LN kernels ----------
// LN1: y = LN(attn(bf16) + tokens(bf16)) -> bf16 (feeds FFN A and residual)
__global__ __launch_bounds__(256) void k_ln1(const __hip_bfloat16* __restrict__ x1,
                                             const __hip_bfloat16* __restrict__ x2,
                                             const float* __restrict__ g,
                                             const float* __restrict__ be,
                                             __hip_bfloat16* __restrict__ y) {
    const int row = blockIdx.x;
    const int tid = threadIdx.x, wid = tid >> 6, lane = tid & 63;
    const int c = tid * 4;
    const ushort4 u = *(const ushort4*)&x1[(size_t)row * 1024 + c];
    const ushort4 u2 = *(const ushort4*)&x2[(size_t)row * 1024 + c];
    float4 xv;
    xv.x = b2f(u.x) + b2f(u2.x);
    xv.y = b2f(u.y) + b2f(u2.y);
    xv.z = b2f(u.z) + b2f(u2.z);
    xv.w = b2f(u.w) + b2f(u2.w);
    float s = xv.x + xv.y + xv.z + xv.w;
    float q = xv.x * xv.x + xv.y * xv.y + xv.z * xv.z + xv.w * xv.w;
#pragma unroll
    for (int msk = 1; msk < 64; msk <<= 1) {
        s += __shfl_xor(s, msk);
        q += __shfl_xor(q, msk);
    }
    __shared__ float ss[4], qq[4];
    if (lane == 0) { ss[wid] = s; qq[wid] = q; }
    __syncthreads();
    s = ss[0] + ss[1] + ss[2] + ss[3];
    q = qq[0] + qq[1] + qq[2] + qq[3];
    const float mu = s * (1.f / 1024.f);
    const float var = q * (1.f / 1024.f) - mu * mu;
    const float rs = rsqrtf(var + 1e-5f);
    float4 gv = *(const float4*)&g[c];
    float4 bv = *(const float4*)&be[c];
    __hip_bfloat16* d = y + (size_t)row * 1024 + c;
    d[0] = f2b((xv.x - mu) * rs * gv.x + bv.x);
    d[1] = f2b((xv.y - mu) * rs * gv.y + bv.y);
    d[2] = f2b((xv.z - mu) * rs * gv.z + bv.z);
    d[3] = f2b((xv.w - mu) * rs * gv.w + bv.w);
}

// LN2: y = LN(x(bf16)) -> f32 (final output)
__global__ __launch_bounds__(256) void k_ln2(const __hip_bfloat16* __restrict__ x,
                                             const float* __restrict__ g,
                                             const float* __restrict__ be,
                                             float* __restrict__ y) {
    const int row = blockIdx.x;
    const int tid = threadIdx.x, wid = tid >> 6, lane = tid & 63;
    const int c = tid * 4;
    const ushort4 u = *(const ushort4*)&x[(size_t)row * 1024 + c];
    float4 xv;
    xv.x = b2f(u.x); xv.y = b2f(u.y); xv.z = b2f(u.z); xv.w = b2f(u.w);
    float s = xv.x + xv.y + xv.z + xv.w;
    float q = xv.x * xv.x + xv.y * xv.y + xv.z * xv.z + xv.w * xv.w;
#pragma unroll
    for (int msk = 1; msk < 64; msk <<= 1) {
        s += __shfl_xor(s, msk);
        q += __shfl_xor(q, msk);
    }
    __shared__ float ss[4], qq[4];
    if (lane == 0) { ss[wid] = s; qq[wid] = q; }
    __syncthreads();
    s = ss[0] + ss[1] + ss[2] + ss[3];
    q = qq[0] + qq[1] + qq[2] + qq[3];
    const float mu = s * (1.f / 1024.f);
    const float var = q * (1.f / 1024.f) - mu * mu;
    const float rs = rsqrtf(var + 1e-5f);
    float4 gv = *(const float4*)&g[c];
    float4 bv = *(const float4*)&be[c];
    float4 yv;
    yv.x = (xv.x - mu) * rs * gv.x + bv.x;
    yv.y = (xv.y - mu) * rs * gv.y + bv.y;
    yv.z = (xv.z - mu) * rs * gv.z + bv.z;
    yv.w = (xv.w - mu) * rs * gv.w + bv.w;
    *(float4*)&y[(size_t)row * 1024 + c] = yv;
}

extern "C" void kernel_launch(void* const* d_in, const int* in_sizes, int n_in,
                              void* d_out, int out_size, void* d_ws, size_t ws_size,
                              hipStream_t stream) {
    const float* tokens = (const float*)d_in[0];
    const float* Wq  = (const float*)d_in[1];
    const float* bq  = (const float*)d_in[2];
    const float* Wk  = (const float*)d_in[3];
    const float* bk  = (const float*)d_in[4];
    const float* Wv  = (const float*)d_in[5];
    const float* bv  = (const float*)d_in[6];
    const float* W1  = (const float*)d_in[7];
    const float* b1  = (const float*)d_in[8];
    const float* W2  = (const float*)d_in[9];
    const float* b2  = (const float*)d_in[10];
    const float* g1  = (const float*)d_in[11];
    const float* be1 = (const float*)d_in[12];
    const float* g2  = (const float*)d_in[13];
    const float* be2 = (const float*)d_in[14];

    char* ws = (char*)d_ws;
    const size_t MB = 1024 * 1024;
    __hip_bfloat16* tok_b  = (__hip_bfloat16*)(ws + 0);
    __hip_bfloat16* Wqkv_t = (__hip_bfloat16*)(ws + 16 * MB);
    __hip_bfloat16* W1t    = (__hip_bfloat16*)(ws + 22 * MB);
    __hip_bfloat16* W2t    = (__hip_bfloat16*)(ws + 24 * MB);
    __hip_bfloat16* Qb     = (__hip_bfloat16*)(ws + 26 * MB);
    __hip_bfloat16* Kb     = (__hip_bfloat16*)(ws + 42 * MB);
    __hip_bfloat16* Vtb    = (__hip_bfloat16*)(ws + 58 * MB);
    __hip_bfloat16* attn_b = (__hip_bfloat16*)(ws + 74 * MB);
    __hip_bfloat16* h1     = (__hip_bfloat16*)(ws + 90 * MB);
    __hip_bfloat16* t1     = (__hip_bfloat16*)(ws + 26 * MB);  // reuse Qb
    __hip_bfloat16* h2     = (__hip_bfloat16*)(ws + 42 * MB);  // reuse Kb

    k_prep<<<9472, 256, 0, stream>>>(tokens, Wq, Wk, Wv, W1, W2,
                                     tok_b, Wqkv_t, W1t, W2t);

    k_gemm<0><<<dim3(24, 64), 512, 0, stream>>>(tok_b, Wqkv_t, bq, bk, bv,
                                                Qb, Kb, Vtb, nullptr);
    k_attn<<<512, 512, 0, stream>>>(Qb, Kb, Vtb, attn_b);
    k_ln1<<<8192, 256, 0, stream>>>(attn_b, tok_b, g1, be1, h1);
    k_gemm<1><<<dim3(8, 64), 512, 0, stream>>>(h1, W1t, b1, nullptr, nullptr,
                                               t1, nullptr, nullptr, nullptr);
    k_gemm<2><<<dim3(8, 64), 512, 0, stream>>>(t1, W2t, b2, nullptr, nullptr,
                                               h2, nullptr, nullptr, h1);
    k_ln2<<<8192, 256, 0, stream>>>(h2, g2, be2, (float*)d_out);
}

// Round 21
// 219.463 us; speedup vs baseline: 1.0708x; 1.0708x over previous
//
#include <hip/hip_runtime.h>
#include <hip/hip_bf16.h>

// Problem constants
#define BB 8
#define NN_ 1024
#define DD 1024
#define HH 16
#define TT_ 64
#define MM (BB * NN_)   // 8192

typedef __attribute__((ext_vector_type(8))) short short8;
typedef __attribute__((ext_vector_type(4))) float f32x4;
typedef __attribute__((ext_vector_type(4))) unsigned int u32x4;

__device__ __forceinline__ void g2lds16(const void* g, void* l) {
    __builtin_amdgcn_global_load_lds(
        (const __attribute__((address_space(1))) void*)g,
        (__attribute__((address_space(3))) void*)l, 16, 0, 0);
}

__device__ __forceinline__ __hip_bfloat16 f2b(float x) { return __float2bfloat16(x); }
__device__ __forceinline__ float b2f(unsigned short u) {
    unsigned v = (unsigned)u << 16;
    return __builtin_bit_cast(float, v);
}

// pack two f32 -> two bf16 in one u32 (lo = a, hi = b)
__device__ __forceinline__ unsigned cvtpk(float a, float b) {
    unsigned r;
    asm("v_cvt_pk_bf16_f32 %0, %1, %2" : "=v"(r) : "v"(a), "v"(b));
    return r;
}

// bijective XCD swizzle (nwg must be divisible by 8): blocks with the same
// (orig % 8) land on one XCD and get a CONTIGUOUS logical range -> L2 reuse.
__device__ __forceinline__ int xcd_swz(int bid, int nwg) {
    return (bid & 7) * (nwg >> 3) + (bid >> 3);
}

// ---------- merged prep kernel ----------
// blocks [0,8192): tokens f32->bf16 ; [8192,8960): Wqkv transpose ;
// [8960,9472): W1/W2 transpose.
__global__ __launch_bounds__(256) void k_prep(const float* __restrict__ tokens,
                                              const float* __restrict__ Wq,
                                              const float* __restrict__ Wk,
                                              const float* __restrict__ Wv,
                                              const float* __restrict__ W1,
                                              const float* __restrict__ W2,
                                              __hip_bfloat16* __restrict__ tok_b,
                                              __hip_bfloat16* __restrict__ Wqkv_t,
                                              __hip_bfloat16* __restrict__ W1t,
                                              __hip_bfloat16* __restrict__ W2t) {
    __shared__ float tile[64][65];
    const int bid = blockIdx.x;
    if (bid < 8192) {
        int i = (bid * 256 + threadIdx.x) * 4;
        float4 v = *(const float4*)&tokens[i];
        tok_b[i + 0] = f2b(v.x); tok_b[i + 1] = f2b(v.y);
        tok_b[i + 2] = f2b(v.z); tok_b[i + 3] = f2b(v.w);
        return;
    }
    const int c = threadIdx.x & 63, r0 = threadIdx.x >> 6;
    if (bid < 8960) {
        const int q = bid - 8192;                 // 0..767
        const int proj = q >> 8, h = (q >> 4) & 15, dt = q & 15;
        const float* W = proj == 0 ? Wq : (proj == 1 ? Wk : Wv);
        const float* src = W + ((size_t)h * 1024 + dt * 64) * 64;   // [64 d][64 t]
#pragma unroll
        for (int p = 0; p < 16; p++) {
            const int r = p * 4 + r0;
            tile[r][c] = src[(size_t)r * 64 + c];
        }
        __syncthreads();
        __hip_bfloat16* dst = Wqkv_t + (size_t)(proj * 1024 + h * 64) * 1024 + dt * 64;
#pragma unroll
        for (int p = 0; p < 16; p++) {
            const int r = p * 4 + r0;   // t index
            dst[(size_t)r * 1024 + c] = f2b(tile[c][r]);
        }
        return;
    }
    const int q = bid - 8960;                     // 0..511
    const int which = q >> 8, b = q & 255;
    const float* W = which ? W2 : W1;
    __hip_bfloat16* out = which ? W2t : W1t;
    const int ct = b & 15, dt = b >> 4;
    const float* src = W + (size_t)(dt * 64) * 1024 + ct * 64;
#pragma unroll
    for (int p = 0; p < 16; p++) {
        const int r = p * 4 + r0;
        tile[r][c] = src[(size_t)r * 1024 + c];
    }
    __syncthreads();
    __hip_bfloat16* dst = out + (size_t)(ct * 64) * 1024 + dt * 64;
#pragma unroll
    for (int p = 0; p < 16; p++) {
        const int r = p * 4 + r0;
        dst[(size_t)r * 1024 + c] = f2b(tile[c][r]);
    }
}

// ---------- GEMM: A[M][1024] bf16  x  Bt[Ncols][1024] bf16 ----------
// Round-13 proven structure: 8 waves / 512 threads, 128x128 tile, BK=64,
// double-buffered LDS, stage -> vmcnt(4) -> barrier -> compute -> barrier.
// T2 XOR-swizzle, setprio, XCD block swizzle.
// MODE 0: proj -> Q (scaled log2e/32), K, Vt (transposed)
// MODE 1: relu(x@W1+b1) -> bf16
// MODE 2: x@W2 + b2 + res(bf16) -> bf16
template <int MODE>
__global__ __launch_bounds__(512) void k_gemm(
    const __hip_bfloat16* __restrict__ A, const __hip_bfloat16* __restrict__ Bt,
    const float* __restrict__ bias0, const float* __restrict__ bias1,
    const float* __restrict__ bias2,
    __hip_bfloat16* __restrict__ ob0, __hip_bfloat16* __restrict__ ob1,
    __hip_bfloat16* __restrict__ ob2,
    const __hip_bfloat16* __restrict__ res) {
    __shared__ __align__(16) __hip_bfloat16 As[2][128 * 64];
    __shared__ __align__(16) __hip_bfloat16 Bs[2][128 * 64];

    const int tid = threadIdx.x;
    const int wid = tid >> 6, lane = tid & 63;
    const int l15 = lane & 15, lhi = lane >> 4;
    const int wm = wid >> 1, wn = wid & 1;   // 4x2 wave grid: 32-row x 64-col sub-tiles

    const int nbx = gridDim.x;
    int bid = xcd_swz(blockIdx.y * nbx + blockIdx.x, nbx * gridDim.y);
    const int n0 = (bid % nbx) * 128, m0 = (bid / nbx) * 128;

    const int srow = lane >> 3;
    const int scol = ((lane & 7) ^ srow) * 8;   // pre-swizzled global source chunk

    const __hip_bfloat16* gsrc;
    if (wid < 4)
        gsrc = A + (size_t)(m0 + wid * 32 + srow) * 1024 + scol;
    else
        gsrc = Bt + (size_t)(n0 + (wid - 4) * 32 + srow) * 1024 + scol;
    const int lofs = (wid & 3) * 2048;   // 32-row chunk within the tile

    // stage K-tile kt into buffer bufi (4 loads/thread; 8 rows per load)
    auto stage = [&](int kt, int bufi) {
        __hip_bfloat16* lb = (wid < 4) ? &As[bufi][lofs] : &Bs[bufi][lofs];
#pragma unroll
        for (int i = 0; i < 4; ++i)
            g2lds16(gsrc + kt * 64 + (size_t)i * 8 * 1024, lb + i * 512);
    };

    f32x4 acc[2][4];
#pragma unroll
    for (int i = 0; i < 2; i++)
#pragma unroll
        for (int j = 0; j < 4; j++) acc[i][j] = (f32x4){0.f, 0.f, 0.f, 0.f};

    stage(0, 0);
    const int swz = l15 & 7;

    for (int kt = 0; kt < 16; ++kt) {
        const int cur = kt & 1;
        if (kt < 15) {
            stage(kt + 1, cur ^ 1);
            asm volatile("s_waitcnt vmcnt(4)" ::: "memory");  // tile kt resident; kt+1 in flight
        } else {
            asm volatile("s_waitcnt vmcnt(0)" ::: "memory");
        }
        __builtin_amdgcn_s_barrier();
        asm volatile("" ::: "memory");
        __builtin_amdgcn_s_setprio(1);
#pragma unroll
        for (int kk = 0; kk < 2; ++kk) {
            const int ch = ((kk * 4 + lhi) ^ swz) * 8;   // swizzled 16B chunk
            short8 af[2], bfr[4];
#pragma unroll
            for (int mi = 0; mi < 2; mi++)
                af[mi] = *(const short8*)&As[cur][(wm * 32 + mi * 16 + l15) * 64 + ch];
#pragma unroll
            for (int ni = 0; ni < 4; ni++)
                bfr[ni] = *(const short8*)&Bs[cur][(wn * 64 + ni * 16 + l15) * 64 + ch];
#pragma unroll
            for (int mi = 0; mi < 2; mi++)
#pragma unroll
                for (int ni = 0; ni < 4; ni++)
                    acc[mi][ni] = __builtin_amdgcn_mfma_f32_16x16x32_bf16(
                        af[mi], bfr[ni], acc[mi][ni], 0, 0, 0);
        }
        __builtin_amdgcn_s_setprio(0);
        asm volatile("" ::: "memory");
        __builtin_amdgcn_s_barrier();   // all waves done reading buf[cur]
    }

#pragma unroll
    for (int mi = 0; mi < 2; mi++) {
#pragma unroll
        for (int ni = 0; ni < 4; ni++) {
            const int col = n0 + wn * 64 + ni * 16 + l15;
#pragma unroll
            for (int r = 0; r < 4; r++) {
                const int m = m0 + wm * 32 + mi * 16 + lhi * 4 + r;
                float v = acc[mi][ni][r];
                if (MODE == 0) {
                    const int proj = col >> 10, hh = (col >> 6) & 15, t = col & 63;
                    const float* bp = proj == 0 ? bias0 : (proj == 1 ? bias1 : bias2);
                    v += bp[hh * 64 + t];
                    const int b = m >> 10, n = m & 1023;
                    if (proj == 0)   // Q pre-scaled by log2(e)/32 (exp2-base softmax)
                        ob0[((size_t)(b * 16 + hh) * 1024 + n) * 64 + t] = f2b(v * 0.04508422f);
                    else if (proj == 1)
                        ob1[((size_t)(b * 16 + hh) * 1024 + n) * 64 + t] = f2b(v);
                    else
                        ob2[((size_t)(b * 16 + hh) * 64 + t) * 1024 + n] = f2b(v);
                } else if (MODE == 1) {
                    v += bias0[col];
                    ob0[(size_t)m * 1024 + col] = f2b(fmaxf(v, 0.f));
                } else {
                    v += bias0[col] + b2f(*(const unsigned short*)&res[(size_t)m * 1024 + col]);
                    ob0[(size_t)m * 1024 + col] = f2b(v);
                }
            }
        }
    }
}

// ---------- flash attention (swapped-QK, in-register P, no-max softmax) ----------
// Round-17 proven form: 8 waves / 512 threads, QBLK=256; KVBLK=128 processed
// as two 64-key halves SEQUENTIALLY per barrier-pair (one half's full
// QK->softmax->PV completes before the next; single live s-state keeps
// VGPR under the no-spill budget -- the h-pipelined variant spilled).
// Proven protocol: stage(t+1) -> vmcnt(4) -> barrier -> compute -> barrier.
// Q,K: [B,H,N,64] bf16 (Q pre-scaled by log2e/32); Vt: [B,H,64,N] bf16
// out: attn [B,N,1024] bf16, channel = t*16 + head
__global__ __launch_bounds__(512) void k_attn(const __hip_bfloat16* __restrict__ Q,
                                              const __hip_bfloat16* __restrict__ Kg,
                                              const __hip_bfloat16* __restrict__ Vt,
                                              __hip_bfloat16* __restrict__ attn_out) {
    __shared__ __align__(16) __hip_bfloat16 Ks[2][2][64 * 64];
    __shared__ __align__(16) __hip_bfloat16 Vs[2][2][64 * 64];

    const int tid = threadIdx.x, wid = tid >> 6, lane = tid & 63;
    const int l15 = lane & 15, lhi = lane >> 4;
    const int bid = xcd_swz(blockIdx.x, gridDim.x);   // XCD x gets one full batch
    const int qb = bid & 3, head = (bid >> 2) & 15, b = bid >> 6;
    const int bh = b * 16 + head;
    const __hip_bfloat16* Qg = Q + ((size_t)bh * 1024 + qb * 256) * 64;
    const __hip_bfloat16* Kp = Kg + (size_t)bh * 1024 * 64;
    const __hip_bfloat16* Vp = Vt + (size_t)bh * 64 * 1024;
    const int srow = lane >> 3;
    const int scol = ((lane & 7) ^ srow) * 8;   // pre-swizzled global source chunk

    // stage 128-key K/V tile t into buffer bufi (4 loads/thread);
    // K rows permuted by pi within each 64-key half.
    auto stageKV = [&](int t, int bufi) {
        const int krow = wid * 8 + srow;                           // row in half, 0..63
        const int kperm = (krow & 0x23) | ((krow & 0x0C) << 1) | ((krow & 0x10) >> 2);
#pragma unroll
        for (int h = 0; h < 2; h++) {
            g2lds16(Kp + (size_t)(t * 128 + h * 64 + kperm) * 64 + scol, &Ks[bufi][h][wid * 512]);
            g2lds16(Vp + (size_t)krow * 1024 + t * 128 + h * 64 + scol, &Vs[bufi][h][wid * 512]);
        }
    };

    // Q fragments straight from global (B-operand: lane l15 = q-row within group)
    short8 qf[2][2];
#pragma unroll
    for (int g = 0; g < 2; g++)
#pragma unroll
        for (int c = 0; c < 2; c++)
            qf[g][c] = *(const short8*)&Qg[(size_t)(wid * 32 + g * 16 + l15) * 64 + c * 32 + lhi * 8];

    stageKV(0, 0);

    f32x4 o[2][4];
#pragma unroll
    for (int g = 0; g < 2; g++)
#pragma unroll
        for (int i = 0; i < 4; i++) o[g][i] = (f32x4){0.f, 0.f, 0.f, 0.f};
    f32x4 lacc[2] = {(f32x4){0.f, 0.f, 0.f, 0.f}, (f32x4){0.f, 0.f, 0.f, 0.f}};
    const short bf16_one = (short)0x3F80;
    const short8 ones = (short8){bf16_one, bf16_one, bf16_one, bf16_one,
                                 bf16_one, bf16_one, bf16_one, bf16_one};

    const int sw = l15 & 7;
    const int c0 = (lhi ^ sw) * 8;   // swizzled chunk for LDS rows with row&7 == l15&7

    for (int t = 0; t < 8; ++t) {
        const int cur = t & 1;
        if (t < 7) {
            stageKV(t + 1, cur ^ 1);
            asm volatile("s_waitcnt vmcnt(4)" ::: "memory");  // tile t resident; t+1 in flight
        } else {
            asm volatile("s_waitcnt vmcnt(0)" ::: "memory");
        }
        __builtin_amdgcn_s_barrier();
        asm volatile("" ::: "memory");

#pragma unroll
        for (int h = 0; h < 2; h++) {
            const __hip_bfloat16* Kc = &Ks[cur][h][0];
            const __hip_bfloat16* Vc = &Vs[cur][h][0];

            // S^T = K Q^T : s[g][nt][r] = S[q][key pi(nt*16+lhi*4+r)] * log2e
            f32x4 s[2][4];
            __builtin_amdgcn_s_setprio(1);
#pragma unroll
            for (int nt = 0; nt < 4; ++nt) {
                const int kr = (nt * 16 + l15) * 64;   // row&7 == sw
                short8 k0 = *(const short8*)&Kc[kr + c0];
                short8 k1 = *(const short8*)&Kc[kr + (c0 ^ 32)];
#pragma unroll
                for (int g = 0; g < 2; g++) {
                    f32x4 z = (f32x4){0.f, 0.f, 0.f, 0.f};
                    z = __builtin_amdgcn_mfma_f32_16x16x32_bf16(k0, qf[g][0], z, 0, 0, 0);
                    s[g][nt] = __builtin_amdgcn_mfma_f32_16x16x32_bf16(k1, qf[g][1], z, 0, 0, 0);
                }
            }
            __builtin_amdgcn_s_setprio(0);

            // p = 2^s (no max subtraction needed; scores bounded)
#pragma unroll
            for (int g = 0; g < 2; g++)
#pragma unroll
                for (int nt = 0; nt < 4; nt++)
#pragma unroll
                    for (int r = 0; r < 4; r++) s[g][nt][r] = __builtin_exp2f(s[g][nt][r]);

            // pack P into PV A-fragments (kpos order == key order by pi construction)
            short8 pf[2][2];
#pragma unroll
            for (int g = 0; g < 2; g++) {
                u32x4 w0 = (u32x4){cvtpk(s[g][0][0], s[g][0][1]), cvtpk(s[g][0][2], s[g][0][3]),
                                   cvtpk(s[g][1][0], s[g][1][1]), cvtpk(s[g][1][2], s[g][1][3])};
                u32x4 w1 = (u32x4){cvtpk(s[g][2][0], s[g][2][1]), cvtpk(s[g][2][2], s[g][2][3]),
                                   cvtpk(s[g][3][0], s[g][3][1]), cvtpk(s[g][3][2], s[g][3][3])};
                pf[g][0] = __builtin_bit_cast(short8, w0);
                pf[g][1] = __builtin_bit_cast(short8, w1);
            }

            // l += P.1 (MFMA row-sum, same C-row mapping as O) ; O += P V
            __builtin_amdgcn_s_setprio(1);
#pragma unroll
            for (int g = 0; g < 2; g++) {
                lacc[g] = __builtin_amdgcn_mfma_f32_16x16x32_bf16(pf[g][0], ones, lacc[g], 0, 0, 0);
                lacc[g] = __builtin_amdgcn_mfma_f32_16x16x32_bf16(pf[g][1], ones, lacc[g], 0, 0, 0);
            }
#pragma unroll
            for (int tt = 0; tt < 4; tt++) {
                const int vr = (tt * 16 + l15) * 64;   // row&7 == sw
                short8 v0 = *(const short8*)&Vc[vr + c0];
                short8 v1 = *(const short8*)&Vc[vr + (c0 ^ 32)];
#pragma unroll
                for (int g = 0; g < 2; g++) {
                    o[g][tt] = __builtin_amdgcn_mfma_f32_16x16x32_bf16(pf[g][0], v0, o[g][tt], 0, 0, 0);
                    o[g][tt] = __builtin_amdgcn_mfma_f32_16x16x32_bf16(pf[g][1], v1, o[g][tt], 0, 0, 0);
                }
            }
            __builtin_amdgcn_s_setprio(0);
        }
        asm volatile("" ::: "memory");
        __builtin_amdgcn_s_barrier();   // all waves done reading buf[cur]
    }

#pragma unroll
    for (int g = 0; g < 2; g++)
#pragma unroll
        for (int r = 0; r < 4; r++) {
            const float inv_r = 1.f / lacc[g][r];
            const int row = qb * 256 + wid * 32 + g * 16 + lhi * 4 + r;
#pragma unroll
            for (int tt = 0; tt < 4; tt++) {
                const int ch = (tt * 16 + l15) * 16 + head;
                attn_out[((size_t)(b * 1024 + row)) * 1024 + ch] = f2b(o[g][tt][r] * inv_r);
            }
        }
}

// ---------- LN kernels ----------
// LN1: y = LN(attn(bf16) + tokens(bf16)) -> bf16 (feeds FFN A and residual)
__global__ __launch_bounds__(256) void k_ln1(const __hip_bfloat16* __restrict__ x1,
                                             const __hip_bfloat16* __restrict__ x2,
                                             const float* __restrict__ g,
                                             const float* __restrict__ be,
                                             __hip_bfloat16* __restrict__ y) {
    const int row = blockIdx.x;
    const int tid = threadIdx.x, wid = tid >> 6, lane = tid & 63;
    const int c = tid * 4;
    const ushort4 u = *(const ushort4*)&x1[(size_t)row * 1024 + c];
    const ushort4 u2 = *(const ushort4*)&x2[(size_t)row * 1024 + c];
    float4 xv;
    xv.x = b2f(u.x) + b2f(u2.x);
    xv.y = b2f(u.y) + b2f(u2.y);
    xv.z = b2f(u.z) + b2f(u2.z);
    xv.w = b2f(u.w) + b2f(u2.w);
    float s = xv.x + xv.y + xv.z + xv.w;
    float q = xv.x * xv.x + xv.y * xv.y + xv.z * xv.z + xv.w * xv.w;
#pragma unroll
    for (int msk = 1; msk < 64; msk <<= 1) {
        s += __shfl_xor(s, msk);
        q += __shfl_xor(q, msk);
    }
    __shared__ float ss[4], qq[4];
    if (lane == 0) { ss[wid] = s; qq[wid] = q; }
    __syncthreads();
    s = ss[0] + ss[1] + ss[2] + ss[3];
    q = qq[0] + qq[1] + qq[2] + qq[3];
    const float mu = s * (1.f / 1024.f);
    const float var = q * (1.f / 1024.f) - mu * mu;
    const float rs = rsqrtf(var + 1e-5f);
    float4 gv = *(const float4*)&g[c];
    float4 bv = *(const float4*)&be[c];
    __hip_bfloat16* d = y + (size_t)row * 1024 + c;
    d[0] = f2b((xv.x - mu) * rs * gv.x + bv.x);
    d[1] = f2b((xv.y - mu) * rs * gv.y + bv.y);
    d[2] = f2b((xv.z - mu) * rs * gv.z + bv.z);
    d[3] = f2b((xv.w - mu) * rs * gv.w + bv.w);
}

// LN2: y = LN(x(bf16)) -> f32 (final output)
__global__ __launch_bounds__(256) void k_ln2(const __hip_bfloat16* __restrict__ x,
                                             const float* __restrict__ g,
                                             const float* __restrict__ be,
                                             float* __restrict__ y) {
    const int row = blockIdx.x;
    const int tid = threadIdx.x, wid = tid >> 6, lane = tid & 63;
    const int c = tid * 4;
    const ushort4 u = *(const ushort4*)&x[(size_t)row * 1024 + c];
    float4 xv;
    xv.x = b2f(u.x); xv.y = b2f(u.y); xv.z = b2f(u.z); xv.w = b2f(u.w);
    float s = xv.x + xv.y + xv.z + xv.w;
    float q = xv.x * xv.x + xv.y * xv.y + xv.z * xv.z + xv.w * xv.w;
#pragma unroll
    for (int msk = 1; msk < 64; msk <<= 1) {
        s += __shfl_xor(s, msk);
        q += __shfl_xor(q, msk);
    }
    __shared__ float ss[4], qq[4];
    if (lane == 0) { ss[wid] = s; qq[wid] = q; }
    __syncthreads();
    s = ss[0] + ss[1] + ss[2] + ss[3];
    q = qq[0] + qq[1] + qq[2] + qq[3];
    const float mu = s * (1.f / 1024.f);
    const float var = q * (1.f / 1024.f) - mu * mu;
    const float rs = rsqrtf(var + 1e-5f);
    float4 gv = *(const float4*)&g[c];
    float4 bv = *(const float4*)&be[c];
    float4 yv;
    yv.x = (xv.x - mu) * rs * gv.x + bv.x;
    yv.y = (xv.y - mu) * rs * gv.y + bv.y;
    yv.z = (xv.z - mu) * rs * gv.z + bv.z;
    yv.w = (xv.w - mu) * rs * gv.w + bv.w;
    *(float4*)&y[(size_t)row * 1024 + c] = yv;
}

extern "C" void kernel_launch(void* const* d_in, const int* in_sizes, int n_in,
                              void* d_out, int out_size, void* d_ws, size_t ws_size,
                              hipStream_t stream) {
    const float* tokens = (const float*)d_in[0];
    const float* Wq  = (const float*)d_in[1];
    const float* bq  = (const float*)d_in[2];
    const float* Wk  = (const float*)d_in[3];
    const float* bk  = (const float*)d_in[4];
    const float* Wv  = (const float*)d_in[5];
    const float* bv  = (const float*)d_in[6];
    const float* W1  = (const float*)d_in[7];
    const float* b1  = (const float*)d_in[8];
    const float* W2  = (const float*)d_in[9];
    const float* b2  = (const float*)d_in[10];
    const float* g1  = (const float*)d_in[11];
    const float* be1 = (const float*)d_in[12];
    const float* g2  = (const float*)d_in[13];
    const float* be2 = (const float*)d_in[14];

    char* ws = (char*)d_ws;
    const size_t MB = 1024 * 1024;
    __hip_bfloat16* tok_b  = (__hip_bfloat16*)(ws + 0);
    __hip_bfloat16* Wqkv_t = (__hip_bfloat16*)(ws + 16 * MB);
    __hip_bfloat16* W1t    = (__hip_bfloat16*)(ws + 22 * MB);
    __hip_bfloat16* W2t    = (__hip_bfloat16*)(ws + 24 * MB);
    __hip_bfloat16* Qb     = (__hip_bfloat16*)(ws + 26 * MB);
    __hip_bfloat16* Kb     = (__hip_bfloat16*)(ws + 42 * MB);
    __hip_bfloat16* Vtb    = (__hip_bfloat16*)(ws + 58 * MB);
    __hip_bfloat16* attn_b = (__hip_bfloat16*)(ws + 74 * MB);
    __hip_bfloat16* h1     = (__hip_bfloat16*)(ws + 90 * MB);
    __hip_bfloat16* t1     = (__hip_bfloat16*)(ws + 26 * MB);  // reuse Qb
    __hip_bfloat16* h2     = (__hip_bfloat16*)(ws + 42 * MB);  // reuse Kb

    k_prep<<<9472, 256, 0, stream>>>(tokens, Wq, Wk, Wv, W1, W2,
                                     tok_b, Wqkv_t, W1t, W2t);

    k_gemm<0><<<dim3(24, 64), 512, 0, stream>>>(tok_b, Wqkv_t, bq, bk, bv,
                                                Qb, Kb, Vtb, nullptr);
    k_attn<<<512, 512, 0, stream>>>(Qb, Kb, Vtb, attn_b);
    k_ln1<<<8192, 256, 0, stream>>>(attn_b, tok_b, g1, be1, h1);
    k_gemm<1><<<dim3(8, 64), 512, 0, stream>>>(h1, W1t, b1, nullptr, nullptr,
                                               t1, nullptr, nullptr, nullptr);
    k_gemm<2><<<dim3(8, 64), 512, 0, stream>>>(t1, W2t, b2, nullptr, nullptr,
                                               h2, nullptr, nullptr, h1);
    k_ln2<<<8192, 256, 0, stream>>>(h2, g2, be2, (float*)d_out);
}